// Round 8
// baseline (167.832 us; speedup 1.0000x reference)
//
#include <hip/hip_runtime.h>

#define NPTS 131072

// ---------- d_ws layout (f32 dword indices) ----------
// gate region (exact f32, const-AS s_load path):
constexpr int OFF_SW1 = 0;        // 1024  select_w1 TRANSPOSED [c*32+e]
constexpr int OFF_BNS = 1024;     // 32
constexpr int OFF_BNH = 1056;     // 32
constexpr int OFF_SW2 = 1088;     // 32
constexpr int OFF_B2  = 1120;     // 1
// LDS-staged f32 table (consecutive, 1823 dwords, 16B-aligned base):
constexpr int TBL  = 1152;
constexpr int TQG  = 1152;   // 608  QG[e*19+k]
constexpr int TA1  = 1760;   // 608  A1[e*19+j]
constexpr int TGVB = 2368;   // 361  GVB[k*19+j]
constexpr int TMVB = 2729;   // 57   MVB[m*19+j]
constexpr int TQM  = 2786;   // 96   QM[e*3+m]
constexpr int TQBV = 2882;   // 32
constexpr int TQGB = 2914;   // 19
constexpr int TBB  = 2933;   // 19
constexpr int TCV  = 2952;   // 19
constexpr int TQMB = 2971;   // 3
constexpr int TQBB = 2974;   // 1
// LDS-local offsets (minus TBL):
constexpr int LQG  = 0,    LA1  = 608,  LGVB = 1216, LMVB = 1577;
constexpr int LQM  = 1634, LQBV = 1730, LQGB = 1762, LBB  = 1781;
constexpr int LCV  = 1800, LQMB = 1819, LQBB = 1822;
// ---- intermediates ----
constexpr int XG   = 3072;  // 608  G[k*32+e]
constexpr int XA2  = 3680;  // 608  A2[d*19+j]
constexpr int XMK  = 4288;  // 96   Mk[m*32+c]
constexpr int XMV  = 4384;  // 96   Mv[m*32+c]
constexpr int XGK  = 4480;  // 608  Gk[k*32+c]
constexpr int XGV  = 5088;  // 608  Gv[k*32+c]
constexpr int XB   = 5696;  // 608  B[c*19+j]

#define CONST_AS __attribute__((address_space(4)))
__device__ __forceinline__ const CONST_AS float* to_const(const float* p) {
    return (const CONST_AS float*)p;
}

// =====================================================================
// Precompute stage A
// =====================================================================
__global__ __launch_bounds__(256) void pre_a(
    const float* __restrict__ z,
    const float* __restrict__ sw1,
    const float* __restrict__ bn_gamma, const float* __restrict__ bn_beta,
    const float* __restrict__ bn_mean,  const float* __restrict__ bn_var,
    const float* __restrict__ sw2,      const float* __restrict__ sb2,
    const float* __restrict__ wq, const float* __restrict__ bq,
    const float* __restrict__ wk, const float* __restrict__ bk,
    const float* __restrict__ wv,
    const float* __restrict__ wt, const float* __restrict__ bt,
    const float* __restrict__ wout, const float* __restrict__ bout,
    const float* __restrict__ wgen, const float* __restrict__ bgen,
    float* __restrict__ W)
{
    int i = blockIdx.x * 256 + threadIdx.x;
    if (i < 1024) {                       // SW1T[c*32+e] = sw1[e*32+c]
        W[OFF_SW1 + i] = sw1[(i & 31) * 32 + (i >> 5)];
    } else if (i < 1632) {                // A1 -> table, A2 -> intermediate
        int t = i - 1024, e = t / 19, j = t % 19;
        float a1 = 0.f, a2 = 0.f;
        for (int d = 0; d < 32; ++d) {
            float w_ = wout[d*19 + j];
            a1 += wt[e*32 + d] * w_;
            a2 += wt[(32 + e)*32 + d] * w_;
        }
        W[TA1 + t] = a1; W[XA2 + t] = a2;
    } else if (i < 2240) {                // G[k*32+e]
        int t = i - 1632, k = t >> 5, e = t & 31;
        float g = bgen[e];
        for (int d = 0; d < 16; ++d) g += z[d] * wgen[d*32 + e];
        W[XG + t] = g + wgen[(16 + k)*32 + e];
    } else if (i < 2336) {                // Mk, Mv
        int t = i - 2240, m = t >> 5, c = t & 31;
        float a = 0.f, b = 0.f;
        for (int e = 0; e < 32; ++e) {
            float wsr = wgen[(35 + m)*32 + e];
            a += wsr * wk[e*32 + c];
            b += wsr * wv[e*32 + c];
        }
        W[XMK + t] = a; W[XMV + t] = b;
    } else if (i < 2368) {                // BN fold + SW2 (gate, f32)
        int t = i - 2336;
        float scale = bn_gamma[t] / sqrtf(bn_var[t] + 1e-4f);
        W[OFF_BNS + t] = scale;
        W[OFF_BNH + t] = bn_beta[t] - bn_mean[t] * scale;
        W[OFF_SW2 + t] = sw2[t];
    } else if (i < 2387) {                // BB
        int t = i - 2368;
        float a = bout[t];
        for (int d = 0; d < 32; ++d) a += bt[d] * wout[d*19 + t];
        W[TBB + t] = a;
    } else if (i < 2419) {                // QBV
        int t = i - 2387;
        float a = 0.f;
        for (int c = 0; c < 32; ++c) a += wq[t*32 + c] * bk[c];
        W[TQBV + t] = a;
    } else if (i == 2419) {
        W[OFF_B2] = sb2[0];
    } else if (i == 2420) {               // QBB
        float a = 0.f;
        for (int c = 0; c < 32; ++c) a += bq[c] * bk[c];
        W[TQBB] = a;
    } else if (i == 2421) {
        W[TBL + 1823] = 0.f;              // pad for float4 staging
    }
}

// =====================================================================
// Precompute stage B
// =====================================================================
__global__ __launch_bounds__(256) void pre_b(
    const float* __restrict__ wq, const float* __restrict__ bq,
    const float* __restrict__ wk, const float* __restrict__ wv,
    const float* __restrict__ wo,
    float* __restrict__ W)
{
    int i = blockIdx.x * 256 + threadIdx.x;
    if (i < 608) {                        // Gk, Gv  [k*32+c]
        int k = i >> 5, c = i & 31;
        float a = 0.f, b = 0.f;
        for (int e = 0; e < 32; ++e) {
            float g = W[XG + k*32 + e];
            a += g * wk[e*32 + c];
            b += g * wv[e*32 + c];
        }
        W[XGK + i] = a; W[XGV + i] = b;
    } else if (i < 1216) {                // B[c*19+j] = wo @ A2
        int t = i - 608, c = t / 19, j = t % 19;
        float a = 0.f;
        for (int d = 0; d < 32; ++d) a += wo[c*32 + d] * W[XA2 + d*19 + j];
        W[XB + t] = a;
    } else if (i < 1312) {                // QM[e*3+m]
        int t = i - 1216, e = t / 3, m = t % 3;
        float a = 0.f;
        for (int c = 0; c < 32; ++c) a += wq[e*32 + c] * W[XMK + m*32 + c];
        W[TQM + t] = a;
    } else if (i < 1315) {                // QMB[m]
        int m = i - 1312;
        float a = 0.f;
        for (int c = 0; c < 32; ++c) a += bq[c] * W[XMK + m*32 + c];
        W[TQMB + m] = a;
    }
}

// =====================================================================
// Precompute stage C: QG, QGB, GVB, MVB, CV (f32, straight into table)
// =====================================================================
__global__ __launch_bounds__(256) void pre_c(
    const float* __restrict__ wq, const float* __restrict__ bq,
    const float* __restrict__ bv, const float* __restrict__ bo,
    float* __restrict__ W)
{
    int i = blockIdx.x * 256 + threadIdx.x;
    if (i < 608) {                        // QG[e*19+k]
        int e = i / 19, k = i % 19;
        float a = 0.f;
        for (int c = 0; c < 32; ++c) a += wq[e*32 + c] * W[XGK + k*32 + c];
        W[TQG + i] = a;
    } else if (i < 627) {                 // QGB[k]
        int k = i - 608;
        float a = 0.f;
        for (int c = 0; c < 32; ++c) a += bq[c] * W[XGK + k*32 + c];
        W[TQGB + k] = a;
    } else if (i < 988) {                 // GVB[k*19+j]
        int t = i - 627, k = t / 19, j = t % 19;
        float a = 0.f;
        for (int c = 0; c < 32; ++c) a += W[XGV + k*32 + c] * W[XB + c*19 + j];
        W[TGVB + t] = a;
    } else if (i < 1045) {                // MVB[m*19+j]
        int t = i - 988, m = t / 19, j = t % 19;
        float a = 0.f;
        for (int c = 0; c < 32; ++c) a += W[XMV + m*32 + c] * W[XB + c*19 + j];
        W[TMVB + t] = a;
    } else if (i < 1064) {                // CV[j]
        int j = i - 1045;
        float a = 0.f;
        for (int c = 0; c < 32; ++c) a += bv[c] * W[XB + c*19 + j];
        for (int d = 0; d < 32; ++d) a += bo[d] * W[XA2 + d*19 + j];
        W[TCV + j] = a;
    }
}

// =====================================================================
// Main kernel: gate exact-f32 via const-AS s_load (scalar pipe);
// attention/output weights f32 in LDS, wave-uniform ds_read broadcast
// (LDS pipe, no conflicts, co-issues with the VALU fma stream).
// =====================================================================
__global__ __launch_bounds__(256, 1) void main_k(
    const float* __restrict__ feat,
    const float* __restrict__ sflow,
    const float* __restrict__ cpred,
    const float* __restrict__ Wg,
    float* __restrict__ out)
{
    const CONST_AS float* W = to_const(Wg);
    const int n = blockIdx.x * 256 + threadIdx.x;
    const int t = threadIdx.x;

    // ---- stage folded table global -> LDS (456 float4) ----
    __shared__ float T[1824];
    {
        const float4* src = (const float4*)(Wg + TBL);
        float4* dst = (float4*)T;
        dst[t] = src[t];                       // 0..255
        if (t < 200) dst[256 + t] = src[256 + t];  // 256..455
    }
    __syncthreads();

    // ---- inputs ----
    float f[32];
    const float4* fp = (const float4*)(feat + (long)n * 32);
#pragma unroll
    for (int g = 0; g < 8; ++g) {
        float4 v = fp[g];
        f[g*4+0] = v.x; f[g*4+1] = v.y; f[g*4+2] = v.z; f[g*4+3] = v.w;
    }
    float s0 = sflow[(long)n*3 + 0];
    float s1 = sflow[(long)n*3 + 1];
    float s2 = sflow[(long)n*3 + 2];
    bool tmask = (s0 != 0.f) | (s1 != 0.f) | (s2 != 0.f);

    // ---- softmax(coarse_pred) ----
    float cp[19];
#pragma unroll
    for (int k = 0; k < 19; ++k) cp[k] = cpred[(long)n*19 + k];
    float m1 = cp[0];
#pragma unroll
    for (int k = 1; k < 19; ++k) m1 = fmaxf(m1, cp[k]);
    float sum1 = 0.f;
#pragma unroll
    for (int k = 0; k < 19; ++k) { cp[k] = __expf(cp[k] - m1); sum1 += cp[k]; }
    float r1 = 1.f / sum1;
#pragma unroll
    for (int k = 0; k < 19; ++k) cp[k] *= r1;

    // ---- gate: exact f32 (const-AS s_load weights, scalar pipe) ----
    float sacc = W[OFF_B2];
#pragma unroll
    for (int c = 0; c < 32; ++c) {
        float a = 0.f;
#pragma unroll
        for (int e = 0; e < 32; ++e) a = fmaf(f[e], W[OFF_SW1 + c*32 + e], a);
        float h = fmaf(a, W[OFF_BNS + c], W[OFF_BNH + c]);
        h = fmaxf(h, 0.f);
        sacc = fmaf(h, W[OFF_SW2 + c], sacc);
    }
    bool valid = tmask && (sacc < 1.3862943611198906f);  // sigmoid<0.8

    // ---- attention logits + f@A1 (LDS weights) ----
    float qg[19], o[19];
#pragma unroll
    for (int k = 0; k < 19; ++k) { qg[k] = T[LQGB + k]; o[k] = T[LBB + k]; }
    float qm0 = T[LQMB + 0], qm1 = T[LQMB + 1], qm2 = T[LQMB + 2];
    float qb = T[LQBB];
#pragma unroll 4
    for (int e = 0; e < 32; ++e) {
        float fe = f[e];
#pragma unroll
        for (int k = 0; k < 19; ++k) {
            qg[k] = fmaf(fe, T[LQG + e*19 + k], qg[k]);
            o[k]  = fmaf(fe, T[LA1 + e*19 + k], o[k]);
        }
        qm0 = fmaf(fe, T[LQM + e*3 + 0], qm0);
        qm1 = fmaf(fe, T[LQM + e*3 + 1], qm1);
        qm2 = fmaf(fe, T[LQM + e*3 + 2], qm2);
        qb  = fmaf(fe, T[LQBV + e], qb);
    }
    float qs = s0*qm0 + s1*qm1 + s2*qm2;

    const float RS = 0.17677669529663687f;  // 1/sqrt(32)
    float l[19];
#pragma unroll
    for (int k = 0; k < 19; ++k) l[k] = fmaf(cp[k], qg[k] + qs, qb) * RS;

    // ---- softmax(l); w[k]=attn[k]*cp[k]; Sw ----
    float m2 = l[0];
#pragma unroll
    for (int k = 1; k < 19; ++k) m2 = fmaxf(m2, l[k]);
    float sum2 = 0.f;
#pragma unroll
    for (int k = 0; k < 19; ++k) { l[k] = __expf(l[k] - m2); sum2 += l[k]; }
    float r2 = 1.f / sum2;
    float Sw = 0.f;
#pragma unroll
    for (int k = 0; k < 19; ++k) { l[k] = l[k] * r2 * cp[k]; Sw += l[k]; }

    // ---- gated part: a2 = CV + Sw*(sf@MVB) + w@GVB ----
    float a2[19];
#pragma unroll
    for (int j = 0; j < 19; ++j) a2[j] = T[LCV + j];
    float cms[3] = { Sw * s0, Sw * s1, Sw * s2 };
#pragma unroll
    for (int m = 0; m < 3; ++m) {
        float cm = cms[m];
#pragma unroll
        for (int j = 0; j < 19; ++j) a2[j] = fmaf(cm, T[LMVB + m*19 + j], a2[j]);
    }
#pragma unroll 4
    for (int k = 0; k < 19; ++k) {
        float lk = l[k];
#pragma unroll
        for (int j = 0; j < 19; ++j) a2[j] = fmaf(lk, T[LGVB + k*19 + j], a2[j]);
    }

    float vg = valid ? 1.f : 0.f;
    float* op = out + (long)n * 19;
#pragma unroll
    for (int j = 0; j < 19; ++j) op[j] = fmaf(vg, a2[j], o[j]);
}

// =====================================================================
extern "C" void kernel_launch(void* const* d_in, const int* in_sizes, int n_in,
                              void* d_out, int out_size, void* d_ws, size_t ws_size,
                              hipStream_t stream) {
    const float* feat  = (const float*)d_in[0];
    const float* sflow = (const float*)d_in[1];
    const float* cpred = (const float*)d_in[2];
    const float* z     = (const float*)d_in[3];
    const float* sw1   = (const float*)d_in[4];
    const float* bn_g  = (const float*)d_in[5];
    const float* bn_b  = (const float*)d_in[6];
    const float* bn_m  = (const float*)d_in[7];
    const float* bn_v  = (const float*)d_in[8];
    const float* sw2   = (const float*)d_in[9];
    const float* sb2   = (const float*)d_in[10];
    const float* wq    = (const float*)d_in[11];
    const float* bq    = (const float*)d_in[12];
    const float* wk    = (const float*)d_in[13];
    const float* bk    = (const float*)d_in[14];
    const float* wv    = (const float*)d_in[15];
    const float* bv    = (const float*)d_in[16];
    const float* wo    = (const float*)d_in[17];
    const float* bo    = (const float*)d_in[18];
    const float* wt    = (const float*)d_in[19];
    const float* bt    = (const float*)d_in[20];
    const float* wout  = (const float*)d_in[21];
    const float* bout  = (const float*)d_in[22];
    const float* wgen  = (const float*)d_in[23];
    const float* bgen  = (const float*)d_in[24];

    float* W = (float*)d_ws;

    hipLaunchKernelGGL(pre_a, dim3(10), dim3(256), 0, stream,
                       z, sw1, bn_g, bn_b, bn_m, bn_v, sw2, sb2,
                       wq, bq, wk, bk, wv, wt, bt, wout, bout, wgen, bgen, W);
    hipLaunchKernelGGL(pre_b, dim3(6), dim3(256), 0, stream,
                       wq, bq, wk, wv, wo, W);
    hipLaunchKernelGGL(pre_c, dim3(5), dim3(256), 0, stream,
                       wq, bq, bv, bo, W);

    hipLaunchKernelGGL(main_k, dim3(NPTS / 256), dim3(256), 0, stream,
                       feat, sflow, cpred, W, (float*)d_out);
}

// Round 9
// 157.870 us; speedup vs baseline: 1.0631x; 1.0631x over previous
//
#include <hip/hip_runtime.h>

#define NPTS 131072
#define HALFN 65536

// ---------- d_ws layout (f32 dword indices) ----------
// gate region (exact f32, const-AS s_load path):
constexpr int OFF_SW1 = 0;        // 1024  select_w1 TRANSPOSED [c*32+e]
constexpr int OFF_BNS = 1024;     // 32
constexpr int OFF_BNH = 1056;     // 32
constexpr int OFF_SW2 = 1088;     // 32
constexpr int OFF_B2  = 1120;     // 1
// LDS-staged f32 table, rows padded to 20 floats (80B, 16B-aligned) so the
// compiler merges wave-uniform reads into ds_read_b128:
constexpr int TBL  = 1152;        // table base in d_ws (16B aligned)
// local (LDS) offsets in floats:
constexpr int LQG  = 0;      // [32][20] QG[e][k]
constexpr int LA1  = 640;    // [32][20] A1[e][j]
constexpr int LGVB = 1280;   // [19][20] GVB[k][j]
constexpr int LMVB = 1660;   // [3][20]  MVB[m][j]
constexpr int LQM  = 1720;   // [32][4]  QM[e][m] (m<3)
constexpr int LQGB = 1848;   // [20]
constexpr int LBB  = 1868;   // [20]
constexpr int LCV  = 1888;   // [20]
constexpr int LQMB = 1908;   // [4]
// table occupies 1912 floats; stage 2048 (512 float4)
// ---- intermediates ----
constexpr int XG   = 3328;  // 608  G[k*32+e]
constexpr int XA2  = 3936;  // 608  A2[d*19+j]
constexpr int XMK  = 4544;  // 96   Mk[m*32+c]
constexpr int XMV  = 4640;  // 96   Mv[m*32+c]
constexpr int XGK  = 4736;  // 608  Gk[k*32+c]
constexpr int XGV  = 5344;  // 608  Gv[k*32+c]
constexpr int XB   = 5952;  // 608  B[c*19+j]

#define CONST_AS __attribute__((address_space(4)))
__device__ __forceinline__ const CONST_AS float* to_const(const float* p) {
    return (const CONST_AS float*)p;
}

// =====================================================================
// Precompute stage A
// =====================================================================
__global__ __launch_bounds__(256) void pre_a(
    const float* __restrict__ z,
    const float* __restrict__ sw1,
    const float* __restrict__ bn_gamma, const float* __restrict__ bn_beta,
    const float* __restrict__ bn_mean,  const float* __restrict__ bn_var,
    const float* __restrict__ sw2,      const float* __restrict__ sb2,
    const float* __restrict__ wk,
    const float* __restrict__ wv,
    const float* __restrict__ wt, const float* __restrict__ bt,
    const float* __restrict__ wout, const float* __restrict__ bout,
    const float* __restrict__ wgen, const float* __restrict__ bgen,
    float* __restrict__ W)
{
    int i = blockIdx.x * 256 + threadIdx.x;
    if (i < 1024) {                       // SW1T[c*32+e] = sw1[e*32+c]
        W[OFF_SW1 + i] = sw1[(i & 31) * 32 + (i >> 5)];
    } else if (i < 1632) {                // A1 -> padded table, A2 -> interm
        int t = i - 1024, e = t / 19, j = t % 19;
        float a1 = 0.f, a2 = 0.f;
        for (int d = 0; d < 32; ++d) {
            float w_ = wout[d*19 + j];
            a1 += wt[e*32 + d] * w_;
            a2 += wt[(32 + e)*32 + d] * w_;
        }
        W[TBL + LA1 + e*20 + j] = a1; W[XA2 + t] = a2;
    } else if (i < 2240) {                // G[k*32+e]
        int t = i - 1632, k = t >> 5, e = t & 31;
        float g = bgen[e];
        for (int d = 0; d < 16; ++d) g += z[d] * wgen[d*32 + e];
        W[XG + t] = g + wgen[(16 + k)*32 + e];
    } else if (i < 2336) {                // Mk, Mv
        int t = i - 2240, m = t >> 5, c = t & 31;
        float a = 0.f, b = 0.f;
        for (int e = 0; e < 32; ++e) {
            float wsr = wgen[(35 + m)*32 + e];
            a += wsr * wk[e*32 + c];
            b += wsr * wv[e*32 + c];
        }
        W[XMK + t] = a; W[XMV + t] = b;
    } else if (i < 2368) {                // BN fold + SW2 (gate, f32)
        int t = i - 2336;
        float scale = bn_gamma[t] / sqrtf(bn_var[t] + 1e-4f);
        W[OFF_BNS + t] = scale;
        W[OFF_BNH + t] = bn_beta[t] - bn_mean[t] * scale;
        W[OFF_SW2 + t] = sw2[t];
    } else if (i < 2387) {                // BB
        int t = i - 2368;
        float a = bout[t];
        for (int d = 0; d < 32; ++d) a += bt[d] * wout[d*19 + t];
        W[TBL + LBB + t] = a;
    } else if (i == 2387) {
        W[OFF_B2] = sb2[0];
    }
}

// =====================================================================
// Precompute stage B
// =====================================================================
__global__ __launch_bounds__(256) void pre_b(
    const float* __restrict__ wq, const float* __restrict__ bq,
    const float* __restrict__ wk, const float* __restrict__ wv,
    const float* __restrict__ wo,
    float* __restrict__ W)
{
    int i = blockIdx.x * 256 + threadIdx.x;
    if (i < 608) {                        // Gk, Gv  [k*32+c]
        int k = i >> 5, c = i & 31;
        float a = 0.f, b = 0.f;
        for (int e = 0; e < 32; ++e) {
            float g = W[XG + k*32 + e];
            a += g * wk[e*32 + c];
            b += g * wv[e*32 + c];
        }
        W[XGK + i] = a; W[XGV + i] = b;
    } else if (i < 1216) {                // B[c*19+j] = wo @ A2
        int t = i - 608, c = t / 19, j = t % 19;
        float a = 0.f;
        for (int d = 0; d < 32; ++d) a += wo[c*32 + d] * W[XA2 + d*19 + j];
        W[XB + t] = a;
    } else if (i < 1312) {                // QM[e][m] -> padded [32][4]
        int t = i - 1216, e = t / 3, m = t % 3;
        float a = 0.f;
        for (int c = 0; c < 32; ++c) a += wq[e*32 + c] * W[XMK + m*32 + c];
        W[TBL + LQM + e*4 + m] = a;
    } else if (i < 1315) {                // QMB[m]
        int m = i - 1312;
        float a = 0.f;
        for (int c = 0; c < 32; ++c) a += bq[c] * W[XMK + m*32 + c];
        W[TBL + LQMB + m] = a;
    }
}

// =====================================================================
// Precompute stage C: QG, QGB, GVB, MVB, CV into padded table
// =====================================================================
__global__ __launch_bounds__(256) void pre_c(
    const float* __restrict__ wq, const float* __restrict__ bq,
    const float* __restrict__ bv, const float* __restrict__ bo,
    float* __restrict__ W)
{
    int i = blockIdx.x * 256 + threadIdx.x;
    if (i < 608) {                        // QG[e][k]
        int e = i / 19, k = i % 19;
        float a = 0.f;
        for (int c = 0; c < 32; ++c) a += wq[e*32 + c] * W[XGK + k*32 + c];
        W[TBL + LQG + e*20 + k] = a;
    } else if (i < 627) {                 // QGB[k]
        int k = i - 608;
        float a = 0.f;
        for (int c = 0; c < 32; ++c) a += bq[c] * W[XGK + k*32 + c];
        W[TBL + LQGB + k] = a;
    } else if (i < 988) {                 // GVB[k][j]
        int t = i - 627, k = t / 19, j = t % 19;
        float a = 0.f;
        for (int c = 0; c < 32; ++c) a += W[XGV + k*32 + c] * W[XB + c*19 + j];
        W[TBL + LGVB + k*20 + j] = a;
    } else if (i < 1045) {                // MVB[m][j]
        int t = i - 988, m = t / 19, j = t % 19;
        float a = 0.f;
        for (int c = 0; c < 32; ++c) a += W[XMV + m*32 + c] * W[XB + c*19 + j];
        W[TBL + LMVB + m*20 + j] = a;
    } else if (i < 1064) {                // CV[j]
        int j = i - 1045;
        float a = 0.f;
        for (int c = 0; c < 32; ++c) a += bv[c] * W[XB + c*19 + j];
        for (int d = 0; d < 32; ++d) a += bo[d] * W[XA2 + d*19 + j];
        W[TBL + LCV + j] = a;
    }
}

// =====================================================================
// Main kernel: TWO points per thread (one weight fetch feeds 2 FMAs).
// Gate exact-f32 via const-AS s_load (scalar pipe, shared between points);
// attention/output weights f32 in LDS with 20-float padded rows so
// wave-uniform reads merge into ds_read_b128 broadcasts (LDS pipe).
// =====================================================================
__global__ __launch_bounds__(256, 1) void main_k(
    const float* __restrict__ feat,
    const float* __restrict__ sflow,
    const float* __restrict__ cpred,
    const float* __restrict__ Wg,
    float* __restrict__ out)
{
    const CONST_AS float* W = to_const(Wg);
    const int t = threadIdx.x;
    const int n0 = blockIdx.x * 256 + t;
    const int n1 = n0 + HALFN;

    // ---- stage folded table global -> LDS (512 float4, 2/thread) ----
    __shared__ float T[2048];
    {
        const float4* src = (const float4*)(Wg + TBL);
        float4* dst = (float4*)T;
        dst[t] = src[t];
        dst[256 + t] = src[256 + t];
    }
    __syncthreads();

    // ---- inputs ----
    float f0[32], f1[32];
    {
        const float4* p0 = (const float4*)(feat + (long)n0 * 32);
        const float4* p1 = (const float4*)(feat + (long)n1 * 32);
#pragma unroll
        for (int g = 0; g < 8; ++g) {
            float4 v = p0[g];
            f0[g*4+0] = v.x; f0[g*4+1] = v.y; f0[g*4+2] = v.z; f0[g*4+3] = v.w;
            float4 u = p1[g];
            f1[g*4+0] = u.x; f1[g*4+1] = u.y; f1[g*4+2] = u.z; f1[g*4+3] = u.w;
        }
    }
    float s00 = sflow[(long)n0*3+0], s01 = sflow[(long)n0*3+1], s02 = sflow[(long)n0*3+2];
    float s10 = sflow[(long)n1*3+0], s11 = sflow[(long)n1*3+1], s12 = sflow[(long)n1*3+2];
    bool tm0 = (s00 != 0.f) | (s01 != 0.f) | (s02 != 0.f);
    bool tm1 = (s10 != 0.f) | (s11 != 0.f) | (s12 != 0.f);

    // ---- softmax(coarse_pred), both points ----
    float cp0[19], cp1[19];
#pragma unroll
    for (int k = 0; k < 19; ++k) {
        cp0[k] = cpred[(long)n0*19 + k];
        cp1[k] = cpred[(long)n1*19 + k];
    }
    float m0 = cp0[0], m1_ = cp1[0];
#pragma unroll
    for (int k = 1; k < 19; ++k) { m0 = fmaxf(m0, cp0[k]); m1_ = fmaxf(m1_, cp1[k]); }
    float su0 = 0.f, su1 = 0.f;
#pragma unroll
    for (int k = 0; k < 19; ++k) {
        cp0[k] = __expf(cp0[k] - m0);  su0 += cp0[k];
        cp1[k] = __expf(cp1[k] - m1_); su1 += cp1[k];
    }
    float ri0 = 1.f / su0, ri1 = 1.f / su1;
#pragma unroll
    for (int k = 0; k < 19; ++k) { cp0[k] *= ri0; cp1[k] *= ri1; }

    // ---- gate: exact f32, s_load weights shared across both points ----
    float sa0 = W[OFF_B2], sa1 = W[OFF_B2];
#pragma unroll 4
    for (int c = 0; c < 32; ++c) {
        float a0 = 0.f, a1 = 0.f;
#pragma unroll
        for (int e = 0; e < 32; ++e) {
            float w_ = W[OFF_SW1 + c*32 + e];
            a0 = fmaf(f0[e], w_, a0);
            a1 = fmaf(f1[e], w_, a1);
        }
        float bs = W[OFF_BNS + c], bh = W[OFF_BNH + c], w2 = W[OFF_SW2 + c];
        float h0 = fmaxf(fmaf(a0, bs, bh), 0.f);
        float h1 = fmaxf(fmaf(a1, bs, bh), 0.f);
        sa0 = fmaf(h0, w2, sa0);
        sa1 = fmaf(h1, w2, sa1);
    }
    bool valid0 = tm0 && (sa0 < 1.3862943611198906f);  // sigmoid<0.8
    bool valid1 = tm1 && (sa1 < 1.3862943611198906f);

    // ---- attention logits + f@A1 (LDS weights, b128 merged) ----
    // note: the q.bk term is k-independent in the logits -> cancels in
    // softmax -> dropped entirely (no QBV/QBB).
    float qg0[19], qg1[19], o0[19], o1[19];
#pragma unroll
    for (int k = 0; k < 19; ++k) {
        float g = T[LQGB + k], b = T[LBB + k];
        qg0[k] = g; qg1[k] = g; o0[k] = b; o1[k] = b;
    }
    float qmA0 = T[LQMB+0], qmA1 = T[LQMB+1], qmA2 = T[LQMB+2];
    float qmB0 = qmA0, qmB1 = qmA1, qmB2 = qmA2;
#pragma unroll 4
    for (int e = 0; e < 32; ++e) {
        float fe0 = f0[e], fe1 = f1[e];
#pragma unroll
        for (int k = 0; k < 19; ++k) {
            float w_ = T[LQG + e*20 + k];
            qg0[k] = fmaf(fe0, w_, qg0[k]);
            qg1[k] = fmaf(fe1, w_, qg1[k]);
        }
#pragma unroll
        for (int k = 0; k < 19; ++k) {
            float w_ = T[LA1 + e*20 + k];
            o0[k] = fmaf(fe0, w_, o0[k]);
            o1[k] = fmaf(fe1, w_, o1[k]);
        }
        float q0 = T[LQM + e*4 + 0], q1 = T[LQM + e*4 + 1], q2 = T[LQM + e*4 + 2];
        qmA0 = fmaf(fe0, q0, qmA0); qmA1 = fmaf(fe0, q1, qmA1); qmA2 = fmaf(fe0, q2, qmA2);
        qmB0 = fmaf(fe1, q0, qmB0); qmB1 = fmaf(fe1, q1, qmB1); qmB2 = fmaf(fe1, q2, qmB2);
    }
    float qs0 = s00*qmA0 + s01*qmA1 + s02*qmA2;
    float qs1 = s10*qmB0 + s11*qmB1 + s12*qmB2;

    const float RS = 0.17677669529663687f;  // 1/sqrt(32)
    float l0[19], l1[19];
#pragma unroll
    for (int k = 0; k < 19; ++k) {
        l0[k] = (cp0[k] * (qg0[k] + qs0)) * RS;
        l1[k] = (cp1[k] * (qg1[k] + qs1)) * RS;
    }

    // ---- softmax(l); w[k]=attn[k]*cp[k]; Sw ----
    float x0 = l0[0], x1 = l1[0];
#pragma unroll
    for (int k = 1; k < 19; ++k) { x0 = fmaxf(x0, l0[k]); x1 = fmaxf(x1, l1[k]); }
    float t0 = 0.f, t1 = 0.f;
#pragma unroll
    for (int k = 0; k < 19; ++k) {
        l0[k] = __expf(l0[k] - x0); t0 += l0[k];
        l1[k] = __expf(l1[k] - x1); t1 += l1[k];
    }
    float r20 = 1.f / t0, r21 = 1.f / t1;
    float Sw0 = 0.f, Sw1 = 0.f;
#pragma unroll
    for (int k = 0; k < 19; ++k) {
        l0[k] = l0[k] * r20 * cp0[k]; Sw0 += l0[k];
        l1[k] = l1[k] * r21 * cp1[k]; Sw1 += l1[k];
    }

    // ---- gated part: a2 = CV + Sw*(sf@MVB) + w@GVB ----
    float a20[19], a21[19];
#pragma unroll
    for (int j = 0; j < 19; ++j) { float c = T[LCV + j]; a20[j] = c; a21[j] = c; }
    float cA0 = Sw0*s00, cA1 = Sw0*s01, cA2 = Sw0*s02;
    float cB0 = Sw1*s10, cB1 = Sw1*s11, cB2 = Sw1*s12;
#pragma unroll
    for (int m = 0; m < 3; ++m) {
        float ca = (m == 0) ? cA0 : (m == 1 ? cA1 : cA2);
        float cb = (m == 0) ? cB0 : (m == 1 ? cB1 : cB2);
#pragma unroll
        for (int j = 0; j < 19; ++j) {
            float w_ = T[LMVB + m*20 + j];
            a20[j] = fmaf(ca, w_, a20[j]);
            a21[j] = fmaf(cb, w_, a21[j]);
        }
    }
#pragma unroll 4
    for (int k = 0; k < 19; ++k) {
        float lk0 = l0[k], lk1 = l1[k];
#pragma unroll
        for (int j = 0; j < 19; ++j) {
            float w_ = T[LGVB + k*20 + j];
            a20[j] = fmaf(lk0, w_, a20[j]);
            a21[j] = fmaf(lk1, w_, a21[j]);
        }
    }

    float vg0 = valid0 ? 1.f : 0.f;
    float vg1 = valid1 ? 1.f : 0.f;
    float* op0 = out + (long)n0 * 19;
    float* op1 = out + (long)n1 * 19;
#pragma unroll
    for (int j = 0; j < 19; ++j) {
        op0[j] = fmaf(vg0, a20[j], o0[j]);
        op1[j] = fmaf(vg1, a21[j], o1[j]);
    }
}

// =====================================================================
extern "C" void kernel_launch(void* const* d_in, const int* in_sizes, int n_in,
                              void* d_out, int out_size, void* d_ws, size_t ws_size,
                              hipStream_t stream) {
    const float* feat  = (const float*)d_in[0];
    const float* sflow = (const float*)d_in[1];
    const float* cpred = (const float*)d_in[2];
    const float* z     = (const float*)d_in[3];
    const float* sw1   = (const float*)d_in[4];
    const float* bn_g  = (const float*)d_in[5];
    const float* bn_b  = (const float*)d_in[6];
    const float* bn_m  = (const float*)d_in[7];
    const float* bn_v  = (const float*)d_in[8];
    const float* sw2   = (const float*)d_in[9];
    const float* sb2   = (const float*)d_in[10];
    const float* wq    = (const float*)d_in[11];
    const float* bq    = (const float*)d_in[12];
    const float* wk    = (const float*)d_in[13];
    const float* bk    = (const float*)d_in[14];  (void)bk;
    const float* wv    = (const float*)d_in[15];
    const float* bv    = (const float*)d_in[16];
    const float* wo    = (const float*)d_in[17];
    const float* bo    = (const float*)d_in[18];
    const float* wt    = (const float*)d_in[19];
    const float* bt    = (const float*)d_in[20];
    const float* wout  = (const float*)d_in[21];
    const float* bout  = (const float*)d_in[22];
    const float* wgen  = (const float*)d_in[23];
    const float* bgen  = (const float*)d_in[24];

    float* W = (float*)d_ws;

    hipLaunchKernelGGL(pre_a, dim3(10), dim3(256), 0, stream,
                       z, sw1, bn_g, bn_b, bn_m, bn_v, sw2, sb2,
                       wk, wv, wt, bt, wout, bout, wgen, bgen, W);
    hipLaunchKernelGGL(pre_b, dim3(6), dim3(256), 0, stream,
                       wq, bq, wk, wv, wo, W);
    hipLaunchKernelGGL(pre_c, dim3(5), dim3(256), 0, stream,
                       wq, bq, bv, bo, W);

    hipLaunchKernelGGL(main_k, dim3(256), dim3(256), 0, stream,
                       feat, sflow, cpred, W, (float*)d_out);
}

// Round 10
// 150.903 us; speedup vs baseline: 1.1122x; 1.0462x over previous
//
#include <hip/hip_runtime.h>

#define NPTS 131072

// ---------- d_ws layout (f32 dword indices) ----------
// gate region (exact f32, const-AS s_load path):
constexpr int OFF_SW1 = 0;        // 1024  select_w1 TRANSPOSED [c*32+e]
constexpr int OFF_BNS = 1024;     // 32
constexpr int OFF_BNH = 1056;     // 32
constexpr int OFF_SW2 = 1088;     // 32
constexpr int OFF_B2  = 1120;     // 1
// LDS-staged f32 table (1912 floats = 478 float4), rows padded for b128:
constexpr int TBL  = 1152;        // base in d_ws (16B aligned)
// local (LDS) offsets in floats:
constexpr int LQA  = 0;      // [32][40]: [e][0..18]=QG[e][k], [e][20..38]=A1[e][j]
constexpr int LGVB = 1280;   // [19][20] GVB[k][j]
constexpr int LMVB = 1660;   // [3][20]  MVB[m][j]
constexpr int LQM  = 1720;   // [32][4]  QM[e][m] (m<3)
constexpr int LQGB = 1848;   // [20]
constexpr int LBB  = 1868;   // [20]
constexpr int LCV  = 1888;   // [20]
constexpr int LQMB = 1908;   // [4]     -> table = 1912 floats total
// ---- intermediates ----
constexpr int XG   = 3328;  // 608  G[k*32+e]
constexpr int XA2  = 3936;  // 608  A2[d*19+j]
constexpr int XMK  = 4544;  // 96   Mk[m*32+c]
constexpr int XMV  = 4640;  // 96   Mv[m*32+c]
constexpr int XGK  = 4736;  // 608  Gk[k*32+c]
constexpr int XGV  = 5344;  // 608  Gv[k*32+c]
constexpr int XB   = 5952;  // 608  B[c*19+j]

#define CONST_AS __attribute__((address_space(4)))
__device__ __forceinline__ const CONST_AS float* to_const(const float* p) {
    return (const CONST_AS float*)p;
}

// =====================================================================
// Precompute stage A
// =====================================================================
__global__ __launch_bounds__(256) void pre_a(
    const float* __restrict__ z,
    const float* __restrict__ sw1,
    const float* __restrict__ bn_gamma, const float* __restrict__ bn_beta,
    const float* __restrict__ bn_mean,  const float* __restrict__ bn_var,
    const float* __restrict__ sw2,      const float* __restrict__ sb2,
    const float* __restrict__ wk,
    const float* __restrict__ wv,
    const float* __restrict__ wt, const float* __restrict__ bt,
    const float* __restrict__ wout, const float* __restrict__ bout,
    const float* __restrict__ wgen, const float* __restrict__ bgen,
    float* __restrict__ W)
{
    int i = blockIdx.x * 256 + threadIdx.x;
    if (i < 1024) {                       // SW1T[c*32+e] = sw1[e*32+c]
        W[OFF_SW1 + i] = sw1[(i & 31) * 32 + (i >> 5)];
    } else if (i < 1632) {                // A1 -> padded table, A2 -> interm
        int t = i - 1024, e = t / 19, j = t % 19;
        float a1 = 0.f, a2 = 0.f;
        for (int d = 0; d < 32; ++d) {
            float w_ = wout[d*19 + j];
            a1 += wt[e*32 + d] * w_;
            a2 += wt[(32 + e)*32 + d] * w_;
        }
        W[TBL + LQA + e*40 + 20 + j] = a1; W[XA2 + t] = a2;
    } else if (i < 2240) {                // G[k*32+e]
        int t = i - 1632, k = t >> 5, e = t & 31;
        float g = bgen[e];
        for (int d = 0; d < 16; ++d) g += z[d] * wgen[d*32 + e];
        W[XG + t] = g + wgen[(16 + k)*32 + e];
    } else if (i < 2336) {                // Mk, Mv
        int t = i - 2240, m = t >> 5, c = t & 31;
        float a = 0.f, b = 0.f;
        for (int e = 0; e < 32; ++e) {
            float wsr = wgen[(35 + m)*32 + e];
            a += wsr * wk[e*32 + c];
            b += wsr * wv[e*32 + c];
        }
        W[XMK + t] = a; W[XMV + t] = b;
    } else if (i < 2368) {                // BN fold + SW2 (gate, f32)
        int t = i - 2336;
        float scale = bn_gamma[t] / sqrtf(bn_var[t] + 1e-4f);
        W[OFF_BNS + t] = scale;
        W[OFF_BNH + t] = bn_beta[t] - bn_mean[t] * scale;
        W[OFF_SW2 + t] = sw2[t];
    } else if (i < 2387) {                // BB
        int t = i - 2368;
        float a = bout[t];
        for (int d = 0; d < 32; ++d) a += bt[d] * wout[d*19 + t];
        W[TBL + LBB + t] = a;
    } else if (i == 2387) {
        W[OFF_B2] = sb2[0];
    } else if (i < 2452) {
        // zero the padding slots so staged float4 reads are defined
        int t = i - 2388;                 // 64 pad candidates: rows' [19] and [39]
        if (t < 32)      W[TBL + LQA + t*40 + 19] = 0.f;
        else             W[TBL + LQA + (t-32)*40 + 39] = 0.f;
    }
}

// =====================================================================
// Precompute stage B
// =====================================================================
__global__ __launch_bounds__(256) void pre_b(
    const float* __restrict__ wq, const float* __restrict__ bq,
    const float* __restrict__ wk, const float* __restrict__ wv,
    const float* __restrict__ wo,
    float* __restrict__ W)
{
    int i = blockIdx.x * 256 + threadIdx.x;
    if (i < 608) {                        // Gk, Gv  [k*32+c]
        int k = i >> 5, c = i & 31;
        float a = 0.f, b = 0.f;
        for (int e = 0; e < 32; ++e) {
            float g = W[XG + k*32 + e];
            a += g * wk[e*32 + c];
            b += g * wv[e*32 + c];
        }
        W[XGK + i] = a; W[XGV + i] = b;
    } else if (i < 1216) {                // B[c*19+j] = wo @ A2
        int t = i - 608, c = t / 19, j = t % 19;
        float a = 0.f;
        for (int d = 0; d < 32; ++d) a += wo[c*32 + d] * W[XA2 + d*19 + j];
        W[XB + t] = a;
    } else if (i < 1312) {                // QM[e][m] -> padded [32][4]
        int t = i - 1216, e = t / 3, m = t % 3;
        float a = 0.f;
        for (int c = 0; c < 32; ++c) a += wq[e*32 + c] * W[XMK + m*32 + c];
        W[TBL + LQM + e*4 + m] = a;
    } else if (i < 1315) {                // QMB[m]
        int m = i - 1312;
        float a = 0.f;
        for (int c = 0; c < 32; ++c) a += bq[c] * W[XMK + m*32 + c];
        W[TBL + LQMB + m] = a;
    } else if (i < 1347) {                // zero QM pad column [e][3]
        int e = i - 1315;
        W[TBL + LQM + e*4 + 3] = 0.f;
    } else if (i == 1347) {
        W[TBL + LQMB + 3] = 0.f;
    }
}

// =====================================================================
// Precompute stage C: QG, QGB, GVB, MVB, CV into padded table
// =====================================================================
__global__ __launch_bounds__(256) void pre_c(
    const float* __restrict__ wq, const float* __restrict__ bq,
    const float* __restrict__ bv, const float* __restrict__ bo,
    float* __restrict__ W)
{
    int i = blockIdx.x * 256 + threadIdx.x;
    if (i < 608) {                        // QG[e][k]
        int e = i / 19, k = i % 19;
        float a = 0.f;
        for (int c = 0; c < 32; ++c) a += wq[e*32 + c] * W[XGK + k*32 + c];
        W[TBL + LQA + e*40 + k] = a;
    } else if (i < 627) {                 // QGB[k]
        int k = i - 608;
        float a = 0.f;
        for (int c = 0; c < 32; ++c) a += bq[c] * W[XGK + k*32 + c];
        W[TBL + LQGB + k] = a;
    } else if (i < 988) {                 // GVB[k][j]
        int t = i - 627, k = t / 19, j = t % 19;
        float a = 0.f;
        for (int c = 0; c < 32; ++c) a += W[XGV + k*32 + c] * W[XB + c*19 + j];
        W[TBL + LGVB + k*20 + j] = a;
    } else if (i < 1045) {                // MVB[m][j]
        int t = i - 988, m = t / 19, j = t % 19;
        float a = 0.f;
        for (int c = 0; c < 32; ++c) a += W[XMV + m*32 + c] * W[XB + c*19 + j];
        W[TBL + LMVB + m*20 + j] = a;
    } else if (i < 1064) {                // CV[j]
        int j = i - 1045;
        float a = 0.f;
        for (int c = 0; c < 32; ++c) a += bv[c] * W[XB + c*19 + j];
        for (int d = 0; d < 32; ++d) a += bo[d] * W[XA2 + d*19 + j];
        W[TBL + LCV + j] = a;
    } else if (i < 1108) {
        // zero remaining pad slots (row [19]/[39] of GVB/MVB, tails of
        // LQGB/LBB/LCV rows)
        int t = i - 1064;
        if (t < 19)      W[TBL + LGVB + t*20 + 19] = 0.f;
        else if (t < 22) W[TBL + LMVB + (t-19)*20 + 19] = 0.f;
        else if (t == 22) W[TBL + LQGB + 19] = 0.f;
        else if (t == 23) W[TBL + LBB + 19] = 0.f;
        else if (t == 24) W[TBL + LCV + 19] = 0.f;
    }
}

// =====================================================================
// Main kernel: 1 point/thread, 512 blocks (8 waves/CU).
// - NO register array is ever dynamically indexed (no scratch):
//   rolled e-loop reads f from per-thread LDS F[e][tid]; all 19-loops
//   fully unrolled.
// - weights: padded LDS rows -> wave-uniform ds_read_b128 broadcasts.
// - gate: exact f32 on the scalar pipe (const-AS s_load), inner e
//   unrolled on register f[e].
// =====================================================================
__global__ __launch_bounds__(256, 2) void main_k(
    const float* __restrict__ feat,
    const float* __restrict__ sflow,
    const float* __restrict__ cpred,
    const float* __restrict__ Wg,
    float* __restrict__ out)
{
    const CONST_AS float* W = to_const(Wg);
    const int t = threadIdx.x;
    const int n = blockIdx.x * 256 + t;

    __shared__ __align__(16) float T[1912];      // folded weights
    __shared__ float F[32 * 256];                // per-thread feat slots

    // ---- stage table global -> LDS (478 float4) ----
    {
        const float4* src = (const float4*)(Wg + TBL);
        float4* dst = (float4*)T;
        dst[t] = src[t];
        if (t < 222) dst[256 + t] = src[256 + t];
    }

    // ---- load feat -> regs, mirror into per-thread LDS ----
    float f[32];
    {
        const float4* fp = (const float4*)(feat + (long)n * 32);
#pragma unroll
        for (int g = 0; g < 8; ++g) {
            float4 v = fp[g];
            f[g*4+0] = v.x; f[g*4+1] = v.y; f[g*4+2] = v.z; f[g*4+3] = v.w;
        }
    }
#pragma unroll
    for (int e = 0; e < 32; ++e) F[e*256 + t] = f[e];
    __syncthreads();

    // ---- scene_flow + temp mask ----
    float s0 = sflow[(long)n*3 + 0];
    float s1 = sflow[(long)n*3 + 1];
    float s2 = sflow[(long)n*3 + 2];
    bool tmask = (s0 != 0.f) | (s1 != 0.f) | (s2 != 0.f);

    // ---- softmax(coarse_pred) (static) ----
    float cp[19];
#pragma unroll
    for (int k = 0; k < 19; ++k) cp[k] = cpred[(long)n*19 + k];
    float m1 = cp[0];
#pragma unroll
    for (int k = 1; k < 19; ++k) m1 = fmaxf(m1, cp[k]);
    float sum1 = 0.f;
#pragma unroll
    for (int k = 0; k < 19; ++k) { cp[k] = __expf(cp[k] - m1); sum1 += cp[k]; }
    float r1 = 1.f / sum1;
#pragma unroll
    for (int k = 0; k < 19; ++k) cp[k] *= r1;

    // ---- gate: exact f32, scalar-pipe weights, rolled c / unrolled e ----
    float sacc = W[OFF_B2];
#pragma unroll 2
    for (int c = 0; c < 32; ++c) {
        float a = 0.f;
#pragma unroll
        for (int e = 0; e < 32; ++e) a = fmaf(f[e], W[OFF_SW1 + c*32 + e], a);
        float h = fmaxf(fmaf(a, W[OFF_BNS + c], W[OFF_BNH + c]), 0.f);
        sacc = fmaf(h, W[OFF_SW2 + c], sacc);
    }
    bool valid = tmask && (sacc < 1.3862943611198906f);  // sigmoid<0.8

    // ---- attention logits + f@A1 (rolled e, LDS b128 weights) ----
    // q.bk term is k-independent -> cancels in softmax -> dropped.
    float qg[19], o[19];
#pragma unroll
    for (int k = 0; k < 19; ++k) { qg[k] = T[LQGB + k]; o[k] = T[LBB + k]; }
    float qm0 = T[LQMB + 0], qm1 = T[LQMB + 1], qm2 = T[LQMB + 2];
#pragma unroll 4
    for (int e = 0; e < 32; ++e) {
        float fe = F[e*256 + t];
#pragma unroll
        for (int k = 0; k < 19; ++k) qg[k] = fmaf(fe, T[LQA + e*40 + k], qg[k]);
#pragma unroll
        for (int k = 0; k < 19; ++k) o[k]  = fmaf(fe, T[LQA + e*40 + 20 + k], o[k]);
        qm0 = fmaf(fe, T[LQM + e*4 + 0], qm0);
        qm1 = fmaf(fe, T[LQM + e*4 + 1], qm1);
        qm2 = fmaf(fe, T[LQM + e*4 + 2], qm2);
    }
    float qs = s0*qm0 + s1*qm1 + s2*qm2;

    const float RS = 0.17677669529663687f;  // 1/sqrt(32)
    float l[19];
#pragma unroll
    for (int k = 0; k < 19; ++k) l[k] = (cp[k] * (qg[k] + qs)) * RS;

    // ---- softmax(l); w[k]=attn[k]*cp[k]; Sw (static) ----
    float m2 = l[0];
#pragma unroll
    for (int k = 1; k < 19; ++k) m2 = fmaxf(m2, l[k]);
    float sum2 = 0.f;
#pragma unroll
    for (int k = 0; k < 19; ++k) { l[k] = __expf(l[k] - m2); sum2 += l[k]; }
    float r2 = 1.f / sum2;
    float Sw = 0.f;
#pragma unroll
    for (int k = 0; k < 19; ++k) { l[k] = l[k] * r2 * cp[k]; Sw += l[k]; }

    // ---- gated part: a2 = CV + Sw*(sf@MVB) + w@GVB (fully unrolled) ----
    float a2[19];
#pragma unroll
    for (int j = 0; j < 19; ++j) a2[j] = T[LCV + j];
    float c0 = Sw * s0, c1 = Sw * s1, c2 = Sw * s2;
#pragma unroll
    for (int j = 0; j < 19; ++j) a2[j] = fmaf(c0, T[LMVB + j], a2[j]);
#pragma unroll
    for (int j = 0; j < 19; ++j) a2[j] = fmaf(c1, T[LMVB + 20 + j], a2[j]);
#pragma unroll
    for (int j = 0; j < 19; ++j) a2[j] = fmaf(c2, T[LMVB + 40 + j], a2[j]);
#pragma unroll
    for (int k = 0; k < 19; ++k) {
        float lk = l[k];
#pragma unroll
        for (int j = 0; j < 19; ++j) a2[j] = fmaf(lk, T[LGVB + k*20 + j], a2[j]);
    }

    float vg = valid ? 1.f : 0.f;
    float* op = out + (long)n * 19;
#pragma unroll
    for (int j = 0; j < 19; ++j) op[j] = fmaf(vg, a2[j], o[j]);
}

// =====================================================================
extern "C" void kernel_launch(void* const* d_in, const int* in_sizes, int n_in,
                              void* d_out, int out_size, void* d_ws, size_t ws_size,
                              hipStream_t stream) {
    const float* feat  = (const float*)d_in[0];
    const float* sflow = (const float*)d_in[1];
    const float* cpred = (const float*)d_in[2];
    const float* z     = (const float*)d_in[3];
    const float* sw1   = (const float*)d_in[4];
    const float* bn_g  = (const float*)d_in[5];
    const float* bn_b  = (const float*)d_in[6];
    const float* bn_m  = (const float*)d_in[7];
    const float* bn_v  = (const float*)d_in[8];
    const float* sw2   = (const float*)d_in[9];
    const float* sb2   = (const float*)d_in[10];
    const float* wq    = (const float*)d_in[11];
    const float* bq    = (const float*)d_in[12];
    const float* wk    = (const float*)d_in[13];
    const float* bk    = (const float*)d_in[14];  (void)bk;
    const float* wv    = (const float*)d_in[15];
    const float* bv    = (const float*)d_in[16];
    const float* wo    = (const float*)d_in[17];
    const float* bo    = (const float*)d_in[18];
    const float* wt    = (const float*)d_in[19];
    const float* bt    = (const float*)d_in[20];
    const float* wout  = (const float*)d_in[21];
    const float* bout  = (const float*)d_in[22];
    const float* wgen  = (const float*)d_in[23];
    const float* bgen  = (const float*)d_in[24];

    float* W = (float*)d_ws;

    hipLaunchKernelGGL(pre_a, dim3(10), dim3(256), 0, stream,
                       z, sw1, bn_g, bn_b, bn_m, bn_v, sw2, sb2,
                       wk, wv, wt, bt, wout, bout, wgen, bgen, W);
    hipLaunchKernelGGL(pre_b, dim3(6), dim3(256), 0, stream,
                       wq, bq, wk, wv, wo, W);
    hipLaunchKernelGGL(pre_c, dim3(5), dim3(256), 0, stream,
                       wq, bq, bv, bo, W);

    hipLaunchKernelGGL(main_k, dim3(512), dim3(256), 0, stream,
                       feat, sflow, cpred, W, (float*)d_out);
}

// Round 12
// 141.658 us; speedup vs baseline: 1.1848x; 1.0653x over previous
//
#include <hip/hip_runtime.h>

#define NPTS 131072

typedef __attribute__((ext_vector_type(8))) short short8;
typedef __attribute__((ext_vector_type(4))) float f32x4;

// ---------- d_ws layout (f32 dword indices) ----------
constexpr int OFF_SW1 = 0;      // 1024 SW1 TRANSPOSED [c*32+e] (gate recompute)
constexpr int OFF_BNS = 1024;   // 32
constexpr int OFF_BNH = 1056;   // 32
constexpr int OFF_SW2 = 1088;   // 32
constexpr int OFF_B2  = 1120;   // 1
constexpr int OFF_QGB = 1121;   // 19
constexpr int OFF_QMB = 1140;   // 3
constexpr int OFF_BB  = 1143;   // 19
constexpr int OFF_CV  = 1162;   // 19
constexpr int OFF_MVB = 1181;   // 57 [m*19+j]
constexpr int EGVB    = 1240;   // 380 = 19x20 padded GVB (16B-aligned)
// B-fragments: 5 tiles x 64 lanes x 8 bf16 = 2560 bf16 = 1280 DWORDS (r11 bug:
// had reserved 640/256 -> FH tiles 3-4 + FL clobbered XA1 -> absmax 4.0)
constexpr int FRAGH   = 1620;   // 1280 dwords: B-frags hi [5][64][8] bf16
constexpr int FRAGL   = 2900;   // 512  dwords: B-frags lo [2][64][8] bf16 (SW1)
// intermediates (now past 3412):
constexpr int XA1 = 3412, XA2 = 4020, XG = 4628, XMK = 5236, XMV = 5332;
constexpr int XGK = 5428, XGV = 6036, XB = 6644, XQG = 7252, XQM = 7860;

#define CONST_AS __attribute__((address_space(4)))
__device__ __forceinline__ const CONST_AS float* to_const(const float* p) {
    return (const CONST_AS float*)p;
}
__device__ __forceinline__ unsigned b16r(float x) {
    unsigned u = __float_as_uint(x);
    return (u + 0x7fffu + ((u >> 16) & 1u)) >> 16;
}
__device__ __forceinline__ float fromb(unsigned h) {
    return __uint_as_float(h << 16);
}

// =====================================================================
// Precompute stage A
// =====================================================================
__global__ __launch_bounds__(256) void pre_a(
    const float* __restrict__ z,
    const float* __restrict__ sw1,
    const float* __restrict__ bn_gamma, const float* __restrict__ bn_beta,
    const float* __restrict__ bn_mean,  const float* __restrict__ bn_var,
    const float* __restrict__ sw2,      const float* __restrict__ sb2,
    const float* __restrict__ wk, const float* __restrict__ wv,
    const float* __restrict__ wt, const float* __restrict__ bt,
    const float* __restrict__ wout, const float* __restrict__ bout,
    const float* __restrict__ wgen, const float* __restrict__ bgen,
    float* __restrict__ W)
{
    int i = blockIdx.x * 256 + threadIdx.x;
    if (i < 1024) {                       // SW1T[c*32+e] = sw1[e*32+c]
        W[OFF_SW1 + i] = sw1[(i & 31) * 32 + (i >> 5)];
    } else if (i < 1632) {                // A1 -> XA1, A2 -> XA2
        int t = i - 1024, e = t / 19, j = t % 19;
        float a1 = 0.f, a2 = 0.f;
        for (int d = 0; d < 32; ++d) {
            float w_ = wout[d*19 + j];
            a1 += wt[e*32 + d] * w_;
            a2 += wt[(32 + e)*32 + d] * w_;
        }
        W[XA1 + t] = a1; W[XA2 + t] = a2;
    } else if (i < 2240) {                // G[k*32+e]
        int t = i - 1632, k = t >> 5, e = t & 31;
        float g = bgen[e];
        for (int d = 0; d < 16; ++d) g += z[d] * wgen[d*32 + e];
        W[XG + t] = g + wgen[(16 + k)*32 + e];
    } else if (i < 2336) {                // Mk, Mv
        int t = i - 2240, m = t >> 5, c = t & 31;
        float a = 0.f, b = 0.f;
        for (int e = 0; e < 32; ++e) {
            float wsr = wgen[(35 + m)*32 + e];
            a += wsr * wk[e*32 + c];
            b += wsr * wv[e*32 + c];
        }
        W[XMK + t] = a; W[XMV + t] = b;
    } else if (i < 2368) {                // BN fold + SW2
        int t = i - 2336;
        float scale = bn_gamma[t] / sqrtf(bn_var[t] + 1e-4f);
        W[OFF_BNS + t] = scale;
        W[OFF_BNH + t] = bn_beta[t] - bn_mean[t] * scale;
        W[OFF_SW2 + t] = sw2[t];
    } else if (i < 2387) {                // BB
        int t = i - 2368;
        float a = bout[t];
        for (int d = 0; d < 32; ++d) a += bt[d] * wout[d*19 + t];
        W[OFF_BB + t] = a;
    } else if (i == 2387) {
        W[OFF_B2] = sb2[0];
    }
}

// =====================================================================
// Precompute stage B
// =====================================================================
__global__ __launch_bounds__(256) void pre_b(
    const float* __restrict__ wq, const float* __restrict__ bq,
    const float* __restrict__ wk, const float* __restrict__ wv,
    const float* __restrict__ wo,
    float* __restrict__ W)
{
    int i = blockIdx.x * 256 + threadIdx.x;
    if (i < 608) {                        // Gk, Gv  [k*32+c]
        int k = i >> 5, c = i & 31;
        float a = 0.f, b = 0.f;
        for (int e = 0; e < 32; ++e) {
            float g = W[XG + k*32 + e];
            a += g * wk[e*32 + c];
            b += g * wv[e*32 + c];
        }
        W[XGK + i] = a; W[XGV + i] = b;
    } else if (i < 1216) {                // B[c*19+j] = wo @ A2
        int t = i - 608, c = t / 19, j = t % 19;
        float a = 0.f;
        for (int d = 0; d < 32; ++d) a += wo[c*32 + d] * W[XA2 + d*19 + j];
        W[XB + t] = a;
    } else if (i < 1312) {                // QM[e*3+m]
        int t = i - 1216, e = t / 3, m = t % 3;
        float a = 0.f;
        for (int c = 0; c < 32; ++c) a += wq[e*32 + c] * W[XMK + m*32 + c];
        W[XQM + t] = a;
    } else if (i < 1315) {                // QMB[m]
        int m = i - 1312;
        float a = 0.f;
        for (int c = 0; c < 32; ++c) a += bq[c] * W[XMK + m*32 + c];
        W[OFF_QMB + m] = a;
    }
}

// =====================================================================
// Precompute stage C
// =====================================================================
__global__ __launch_bounds__(256) void pre_c(
    const float* __restrict__ wq, const float* __restrict__ bq,
    const float* __restrict__ bv, const float* __restrict__ bo,
    float* __restrict__ W)
{
    int i = blockIdx.x * 256 + threadIdx.x;
    if (i < 608) {                        // QG[e*19+k] -> XQG
        int e = i / 19, k = i % 19;
        float a = 0.f;
        for (int c = 0; c < 32; ++c) a += wq[e*32 + c] * W[XGK + k*32 + c];
        W[XQG + i] = a;
    } else if (i < 627) {                 // QGB[k]
        int k = i - 608;
        float a = 0.f;
        for (int c = 0; c < 32; ++c) a += bq[c] * W[XGK + k*32 + c];
        W[OFF_QGB + k] = a;
    } else if (i < 988) {                 // EGVB[k*20+j]
        int t = i - 627, k = t / 19, j = t % 19;
        float a = 0.f;
        for (int c = 0; c < 32; ++c) a += W[XGV + k*32 + c] * W[XB + c*19 + j];
        W[EGVB + k*20 + j] = a;
    } else if (i < 1007) {                // EGVB pad col
        int k = i - 988;
        W[EGVB + k*20 + 19] = 0.f;
    } else if (i < 1064) {                // MVB[m*19+j]
        int t = i - 1007, m = t / 19, j = t % 19;
        float a = 0.f;
        for (int c = 0; c < 32; ++c) a += W[XMV + m*32 + c] * W[XB + c*19 + j];
        W[OFF_MVB + t] = a;
    } else if (i < 1083) {                // CV[j]
        int j = i - 1064;
        float a = 0.f;
        for (int c = 0; c < 32; ++c) a += bv[c] * W[XB + c*19 + j];
        for (int d = 0; d < 32; ++d) a += bo[d] * W[XA2 + d*19 + j];
        W[OFF_CV + j] = a;
    }
}

// =====================================================================
// Precompute stage D: emit MFMA B-fragments for Wc=[SW1|QG|A1|QM|0pad]
// B[k][n]: lane l holds B[(l>>4)*8+j][16T+(l&15)], j=0..7 (bf16)
// =====================================================================
__global__ __launch_bounds__(256) void pre_d(
    const float* __restrict__ sw1, float* __restrict__ W)
{
    int i = blockIdx.x * 256 + threadIdx.x;
    unsigned short* FH = (unsigned short*)(W + FRAGH);
    unsigned short* FL = (unsigned short*)(W + FRAGL);
    if (i < 2560) {
        int T = i >> 9, l = (i >> 3) & 63, j = i & 7;
        int e = ((l >> 4) << 3) + j, col = 16*T + (l & 15);
        float v;
        if      (col < 32) v = sw1[e*32 + col];
        else if (col < 51) v = W[XQG + e*19 + (col - 32)];
        else if (col < 70) v = W[XA1 + e*19 + (col - 51)];
        else if (col < 73) v = W[XQM + e*3  + (col - 70)];
        else               v = 0.f;
        FH[(T*64 + l)*8 + j] = (unsigned short)b16r(v);
    } else if (i < 3584) {
        int i2 = i - 2560;
        int T = i2 >> 9, l = (i2 >> 3) & 63, j = i2 & 7;
        int e = ((l >> 4) << 3) + j, col = 16*T + (l & 15);
        float v = sw1[e*32 + col];            // T<2 -> col<32 always
        float vh = fromb(b16r(v));
        FL[(T*64 + l)*8 + j] = (unsigned short)b16r(v - vh);
    }
}

// =====================================================================
// Main kernel: MFMA phase (U = feat@Wc per 16-point tile) -> LDS ->
// per-thread scalar epilogue (r10-proven math).
// =====================================================================
__global__ __launch_bounds__(256, 2) void main_k(
    const float* __restrict__ feat,
    const float* __restrict__ sflow,
    const float* __restrict__ cpred,
    const float* __restrict__ Wg,
    float* __restrict__ out)
{
    const CONST_AS float* W = to_const(Wg);
    const int t = threadIdx.x, lane = t & 63, wvi = t >> 6;
    const int pblk = blockIdx.x * 256;

    __shared__ __align__(16) float HF[32 * 264];            // H cols, f32
    __shared__ __align__(16) unsigned short OH[41 * 264];   // logits/O1/QM, bf16
    __shared__ __align__(16) float GV[380];                 // GVB 19x20

    if (t < 95) ((float4*)GV)[t] = ((const float4*)(Wg + EGVB))[t];

    // ---- loop-invariant B fragments (7 x 16B per lane) ----
    const short8* FH8 = (const short8*)(Wg + FRAGH);
    const short8* FL8 = (const short8*)(Wg + FRAGL);
    short8 bh0 = FH8[0*64 + lane], bh1 = FH8[1*64 + lane];
    short8 bh2 = FH8[2*64 + lane], bh3 = FH8[3*64 + lane];
    short8 bh4 = FH8[4*64 + lane];
    short8 bl0 = FL8[0*64 + lane], bl1 = FL8[1*64 + lane];

    const int n15 = lane & 15, q = lane >> 4;

    // ---- 4 tiles of 16 points per wave ----
#pragma unroll
    for (int tile = 0; tile < 4; ++tile) {
        const int p0 = wvi*64 + tile*16;
        const float* fr = feat + (long)(pblk + p0 + n15) * 32 + q*8;
        float xv[8];
        {
            float4 va = *(const float4*)fr;
            float4 vb = *(const float4*)(fr + 4);
            xv[0]=va.x; xv[1]=va.y; xv[2]=va.z; xv[3]=va.w;
            xv[4]=vb.x; xv[5]=vb.y; xv[6]=vb.z; xv[7]=vb.w;
        }
        short8 ah, al;
#pragma unroll
        for (int j = 0; j < 8; ++j) {
            unsigned h = b16r(xv[j]);
            ah[j] = (short)h;
            al[j] = (short)b16r(xv[j] - fromb(h));
        }
        f32x4 z4 = {0.f, 0.f, 0.f, 0.f};
        f32x4 aH0, aH1, a2_, a3_, a4_;
        aH0 = __builtin_amdgcn_mfma_f32_16x16x32_bf16(ah, bh0, z4, 0, 0, 0);
        aH0 = __builtin_amdgcn_mfma_f32_16x16x32_bf16(ah, bl0, aH0, 0, 0, 0);
        aH0 = __builtin_amdgcn_mfma_f32_16x16x32_bf16(al, bh0, aH0, 0, 0, 0);
        aH1 = __builtin_amdgcn_mfma_f32_16x16x32_bf16(ah, bh1, z4, 0, 0, 0);
        aH1 = __builtin_amdgcn_mfma_f32_16x16x32_bf16(ah, bl1, aH1, 0, 0, 0);
        aH1 = __builtin_amdgcn_mfma_f32_16x16x32_bf16(al, bh1, aH1, 0, 0, 0);
        a2_ = __builtin_amdgcn_mfma_f32_16x16x32_bf16(ah, bh2, z4, 0, 0, 0);
        a3_ = __builtin_amdgcn_mfma_f32_16x16x32_bf16(ah, bh3, z4, 0, 0, 0);
        a4_ = __builtin_amdgcn_mfma_f32_16x16x32_bf16(ah, bh4, z4, 0, 0, 0);

        // C layout: col=lane&15, row(point)=q*4+reg  ->  [col][point] stores
        *(f32x4*)&HF[(n15)      * 264 + p0 + q*4] = aH0;   // H cols 0..15
        *(f32x4*)&HF[(16 + n15) * 264 + p0 + q*4] = aH1;   // H cols 16..31
        {   // bf16 cols: OH row r = Wc col 32+r
            unsigned d0, d1;
            d0 = b16r(a2_[0]) | (b16r(a2_[1]) << 16);
            d1 = b16r(a2_[2]) | (b16r(a2_[3]) << 16);
            *(uint2*)&OH[(n15) * 264 + p0 + q*4] = make_uint2(d0, d1);
            d0 = b16r(a3_[0]) | (b16r(a3_[1]) << 16);
            d1 = b16r(a3_[2]) | (b16r(a3_[3]) << 16);
            *(uint2*)&OH[(16 + n15) * 264 + p0 + q*4] = make_uint2(d0, d1);
            if (n15 <= 8) {
                d0 = b16r(a4_[0]) | (b16r(a4_[1]) << 16);
                d1 = b16r(a4_[2]) | (b16r(a4_[3]) << 16);
                *(uint2*)&OH[(32 + n15) * 264 + p0 + q*4] = make_uint2(d0, d1);
            }
        }
    }
    __syncthreads();

    // =========== epilogue: thread t handles point p ===========
    const long p = pblk + t;

    float s0 = sflow[p*3 + 0], s1 = sflow[p*3 + 1], s2 = sflow[p*3 + 2];
    bool tmask = (s0 != 0.f) | (s1 != 0.f) | (s2 != 0.f);

    float cp[19];
#pragma unroll
    for (int k = 0; k < 19; ++k) cp[k] = cpred[p*19 + k];
    float m1 = cp[0];
#pragma unroll
    for (int k = 1; k < 19; ++k) m1 = fmaxf(m1, cp[k]);
    float sum1 = 0.f;
#pragma unroll
    for (int k = 0; k < 19; ++k) { cp[k] = __expf(cp[k] - m1); sum1 += cp[k]; }
    float r1 = 1.f / sum1;
#pragma unroll
    for (int k = 0; k < 19; ++k) cp[k] *= r1;

    // ---- gate from mfma H (split-bf16, err ~1e-4) ----
    const float TH = 1.3862943611198906f;   // ln(4): sigmoid<0.8
    float sacc = W[OFF_B2];
#pragma unroll
    for (int c = 0; c < 32; ++c) {
        float a = HF[c*264 + t];
        float h = fmaxf(fmaf(a, W[OFF_BNS + c], W[OFF_BNH + c]), 0.f);
        sacc = fmaf(h, W[OFF_SW2 + c], sacc);
    }
    // margin safety net: exact f32 recompute for near-threshold points
    bool nearthr = fabsf(sacc - TH) < 1e-3f;
    if (__ballot(nearthr) != 0ULL) {
        float f[32];
        const float4* fp4 = (const float4*)(feat + p*32);
#pragma unroll
        for (int g = 0; g < 8; ++g) {
            float4 v = fp4[g];
            f[g*4+0]=v.x; f[g*4+1]=v.y; f[g*4+2]=v.z; f[g*4+3]=v.w;
        }
        float sr = W[OFF_B2];
        for (int c = 0; c < 32; ++c) {
            float a = 0.f;
#pragma unroll
            for (int e = 0; e < 32; ++e) a = fmaf(f[e], W[OFF_SW1 + c*32 + e], a);
            float h = fmaxf(fmaf(a, W[OFF_BNS + c], W[OFF_BNH + c]), 0.f);
            sr = fmaf(h, W[OFF_SW2 + c], sr);
        }
        sacc = nearthr ? sr : sacc;
    }
    bool valid = tmask && (sacc < TH);

    // ---- logits / qs from mfma U ----
    float qm0 = fromb(OH[38*264 + t]) + W[OFF_QMB + 0];
    float qm1 = fromb(OH[39*264 + t]) + W[OFF_QMB + 1];
    float qm2 = fromb(OH[40*264 + t]) + W[OFF_QMB + 2];
    float qs = s0*qm0 + s1*qm1 + s2*qm2;

    const float RS = 0.17677669529663687f;  // 1/sqrt(32)
    float l[19];
#pragma unroll
    for (int k = 0; k < 19; ++k)
        l[k] = (cp[k] * (fromb(OH[k*264 + t]) + W[OFF_QGB + k] + qs)) * RS;

    float m2 = l[0];
#pragma unroll
    for (int k = 1; k < 19; ++k) m2 = fmaxf(m2, l[k]);
    float sum2 = 0.f;
#pragma unroll
    for (int k = 0; k < 19; ++k) { l[k] = __expf(l[k] - m2); sum2 += l[k]; }
    float r2 = 1.f / sum2;
    float Sw = 0.f;
#pragma unroll
    for (int k = 0; k < 19; ++k) { l[k] = l[k] * r2 * cp[k]; Sw += l[k]; }

    // ---- o = U_A1 + BB ----
    float o[19];
#pragma unroll
    for (int j = 0; j < 19; ++j) o[j] = fromb(OH[(19 + j)*264 + t]) + W[OFF_BB + j];

    // ---- a2 = CV + Sw*(sf@MVB) + w@GVB ----
    float a2[19];
    float c0 = Sw * s0, c1 = Sw * s1, c2 = Sw * s2;
#pragma unroll
    for (int j = 0; j < 19; ++j)
        a2[j] = W[OFF_CV + j] + c0 * W[OFF_MVB + j]
              + c1 * W[OFF_MVB + 19 + j] + c2 * W[OFF_MVB + 38 + j];
#pragma unroll
    for (int k = 0; k < 19; ++k) {
        float lk = l[k];
#pragma unroll
        for (int j = 0; j < 19; ++j) a2[j] = fmaf(lk, GV[k*20 + j], a2[j]);
    }

    float vg = valid ? 1.f : 0.f;
    float* op = out + p * 19;
#pragma unroll
    for (int j = 0; j < 19; ++j) op[j] = fmaf(vg, a2[j], o[j]);
}

// =====================================================================
extern "C" void kernel_launch(void* const* d_in, const int* in_sizes, int n_in,
                              void* d_out, int out_size, void* d_ws, size_t ws_size,
                              hipStream_t stream) {
    const float* feat  = (const float*)d_in[0];
    const float* sflow = (const float*)d_in[1];
    const float* cpred = (const float*)d_in[2];
    const float* z     = (const float*)d_in[3];
    const float* sw1   = (const float*)d_in[4];
    const float* bn_g  = (const float*)d_in[5];
    const float* bn_b  = (const float*)d_in[6];
    const float* bn_m  = (const float*)d_in[7];
    const float* bn_v  = (const float*)d_in[8];
    const float* sw2   = (const float*)d_in[9];
    const float* sb2   = (const float*)d_in[10];
    const float* wq    = (const float*)d_in[11];
    const float* bq    = (const float*)d_in[12];
    const float* wk    = (const float*)d_in[13];
    const float* bk    = (const float*)d_in[14];  (void)bk;
    const float* wv    = (const float*)d_in[15];
    const float* bv    = (const float*)d_in[16];
    const float* wo    = (const float*)d_in[17];
    const float* bo    = (const float*)d_in[18];
    const float* wt    = (const float*)d_in[19];
    const float* bt    = (const float*)d_in[20];
    const float* wout  = (const float*)d_in[21];
    const float* bout  = (const float*)d_in[22];
    const float* wgen  = (const float*)d_in[23];
    const float* bgen  = (const float*)d_in[24];

    float* W = (float*)d_ws;

    hipLaunchKernelGGL(pre_a, dim3(10), dim3(256), 0, stream,
                       z, sw1, bn_g, bn_b, bn_m, bn_v, sw2, sb2,
                       wk, wv, wt, bt, wout, bout, wgen, bgen, W);
    hipLaunchKernelGGL(pre_b, dim3(6), dim3(256), 0, stream,
                       wq, bq, wk, wv, wo, W);
    hipLaunchKernelGGL(pre_c, dim3(5), dim3(256), 0, stream,
                       wq, bq, bv, bo, W);
    hipLaunchKernelGGL(pre_d, dim3(14), dim3(256), 0, stream,
                       sw1, W);

    hipLaunchKernelGGL(main_k, dim3(512), dim3(256), 0, stream,
                       feat, sflow, cpred, W, (float*)d_out);
}

// Round 13
// 140.175 us; speedup vs baseline: 1.1973x; 1.0106x over previous
//
#include <hip/hip_runtime.h>

#define NPTS 131072

typedef __attribute__((ext_vector_type(8))) short short8;
typedef __attribute__((ext_vector_type(4))) float f32x4;

// ---------- d_ws layout (f32 dword indices) ----------
constexpr int OFF_SW1 = 0;      // 1024 SW1 TRANSPOSED [c*32+e] (gate recompute)
constexpr int OFF_BNS = 1024;   // 32
constexpr int OFF_BNH = 1056;   // 32
constexpr int OFF_SW2 = 1088;   // 32
constexpr int OFF_B2  = 1120;   // 1
constexpr int OFF_QGB = 1121;   // 19
constexpr int OFF_QMB = 1140;   // 3
constexpr int OFF_BB  = 1143;   // 19
constexpr int OFF_CV  = 1162;   // 19
constexpr int OFF_MVB = 1181;   // 57 [m*19+j]
constexpr int EGVB    = 1240;   // 380 = 19x20 padded GVB (16B-aligned)
constexpr int FRAGH   = 1620;   // 1280 dwords: B-frags hi [5][64][8] bf16
constexpr int FRAGL   = 2900;   // 512  dwords: B-frags lo [2][64][8] bf16 (SW1)
// intermediates:
constexpr int XA2 = 4020, XG = 4628, XMK = 5236, XMV = 5332;
constexpr int XGK = 5428, XGV = 6036, XB = 6644;

#define CONST_AS __attribute__((address_space(4)))
__device__ __forceinline__ const CONST_AS float* to_const(const float* p) {
    return (const CONST_AS float*)p;
}
__device__ __forceinline__ unsigned b16r(float x) {
    unsigned u = __float_as_uint(x);
    return (u + 0x7fffu + ((u >> 16) & 1u)) >> 16;
}
__device__ __forceinline__ float fromb(unsigned h) {
    return __uint_as_float(h << 16);
}
// inverse fragment map: value for (e=k-dim, col) -> FH[(T*64+l)*8+jj]
__device__ __forceinline__ int fragidx(int e, int col) {
    int T = col >> 4, l = (col & 15) + ((e >> 3) << 4), jj = e & 7;
    return (T * 64 + l) * 8 + jj;
}

// =====================================================================
// Precompute stage A (also emits SW1 hi/lo + A1 + pad fragments)
// =====================================================================
__global__ __launch_bounds__(256) void pre_a(
    const float* __restrict__ z,
    const float* __restrict__ sw1,
    const float* __restrict__ bn_gamma, const float* __restrict__ bn_beta,
    const float* __restrict__ bn_mean,  const float* __restrict__ bn_var,
    const float* __restrict__ sw2,      const float* __restrict__ sb2,
    const float* __restrict__ wk, const float* __restrict__ wv,
    const float* __restrict__ wt, const float* __restrict__ bt,
    const float* __restrict__ wout, const float* __restrict__ bout,
    const float* __restrict__ wgen, const float* __restrict__ bgen,
    float* __restrict__ W)
{
    int i = blockIdx.x * 256 + threadIdx.x;
    unsigned short* FH = (unsigned short*)(W + FRAGH);
    unsigned short* FL = (unsigned short*)(W + FRAGL);
    if (i < 1024) {                       // SW1T[c*32+e] = sw1[e*32+c]
        W[OFF_SW1 + i] = sw1[(i & 31) * 32 + (i >> 5)];
    } else if (i < 1632) {                // A1 -> fragment, A2 -> interm
        int t = i - 1024, e = t / 19, j = t % 19;
        float a1 = 0.f, a2 = 0.f;
        for (int d = 0; d < 32; ++d) {
            float w_ = wout[d*19 + j];
            a1 += wt[e*32 + d] * w_;
            a2 += wt[(32 + e)*32 + d] * w_;
        }
        FH[fragidx(e, 51 + j)] = (unsigned short)b16r(a1);
        W[XA2 + t] = a2;
    } else if (i < 2240) {                // G[k*32+e]
        int t = i - 1632, k = t >> 5, e = t & 31;
        float g = bgen[e];
        for (int d = 0; d < 16; ++d) g += z[d] * wgen[d*32 + e];
        W[XG + t] = g + wgen[(16 + k)*32 + e];
    } else if (i < 2336) {                // Mk, Mv
        int t = i - 2240, m = t >> 5, c = t & 31;
        float a = 0.f, b = 0.f;
        for (int e = 0; e < 32; ++e) {
            float wsr = wgen[(35 + m)*32 + e];
            a += wsr * wk[e*32 + c];
            b += wsr * wv[e*32 + c];
        }
        W[XMK + t] = a; W[XMV + t] = b;
    } else if (i < 2368) {                // BN fold + SW2
        int t = i - 2336;
        float scale = bn_gamma[t] / sqrtf(bn_var[t] + 1e-4f);
        W[OFF_BNS + t] = scale;
        W[OFF_BNH + t] = bn_beta[t] - bn_mean[t] * scale;
        W[OFF_SW2 + t] = sw2[t];
    } else if (i < 2387) {                // BB
        int t = i - 2368;
        float a = bout[t];
        for (int d = 0; d < 32; ++d) a += bt[d] * wout[d*19 + t];
        W[OFF_BB + t] = a;
    } else if (i == 2387) {
        W[OFF_B2] = sb2[0];
    } else if (i < 3412) {                // SW1 hi fragments (tiles 0-1)
        int idx = i - 2388;
        int T = idx >> 9, rem = idx & 511, l = rem >> 3, j = rem & 7;
        int e = ((l >> 4) << 3) + j, col = 16*T + (l & 15);
        FH[(T*64 + l)*8 + j] = (unsigned short)b16r(sw1[e*32 + col]);
    } else if (i < 4436) {                // SW1 lo fragments
        int idx = i - 3412;
        int T = idx >> 9, rem = idx & 511, l = rem >> 3, j = rem & 7;
        int e = ((l >> 4) << 3) + j, col = 16*T + (l & 15);
        float v = sw1[e*32 + col];
        FL[(T*64 + l)*8 + j] = (unsigned short)b16r(v - fromb(b16r(v)));
    } else if (i < 4660) {                // pad cols 73..79 of tile 4 = 0
        int idx = i - 4436;
        int col = 73 + idx / 32, rem = idx & 31, q = rem >> 3, j2 = rem & 7;
        int l = (col & 15) + (q << 4);
        FH[(4*64 + l)*8 + j2] = 0;
    }
}

// =====================================================================
// Precompute stage B (also emits QM fragments)
// =====================================================================
__global__ __launch_bounds__(256) void pre_b(
    const float* __restrict__ wq, const float* __restrict__ bq,
    const float* __restrict__ wk, const float* __restrict__ wv,
    const float* __restrict__ wo,
    float* __restrict__ W)
{
    int i = blockIdx.x * 256 + threadIdx.x;
    unsigned short* FH = (unsigned short*)(W + FRAGH);
    if (i < 608) {                        // Gk, Gv  [k*32+c]
        int k = i >> 5, c = i & 31;
        float a = 0.f, b = 0.f;
        for (int e = 0; e < 32; ++e) {
            float g = W[XG + k*32 + e];
            a += g * wk[e*32 + c];
            b += g * wv[e*32 + c];
        }
        W[XGK + i] = a; W[XGV + i] = b;
    } else if (i < 1216) {                // B[c*19+j] = wo @ A2
        int t = i - 608, c = t / 19, j = t % 19;
        float a = 0.f;
        for (int d = 0; d < 32; ++d) a += wo[c*32 + d] * W[XA2 + d*19 + j];
        W[XB + t] = a;
    } else if (i < 1312) {                // QM[e][m] -> fragment col 70+m
        int t = i - 1216, e = t / 3, m = t % 3;
        float a = 0.f;
        for (int c = 0; c < 32; ++c) a += wq[e*32 + c] * W[XMK + m*32 + c];
        FH[fragidx(e, 70 + m)] = (unsigned short)b16r(a);
    } else if (i < 1315) {                // QMB[m]
        int m = i - 1312;
        float a = 0.f;
        for (int c = 0; c < 32; ++c) a += bq[c] * W[XMK + m*32 + c];
        W[OFF_QMB + m] = a;
    }
}

// =====================================================================
// Precompute stage C (also emits QG fragments)
// =====================================================================
__global__ __launch_bounds__(256) void pre_c(
    const float* __restrict__ wq, const float* __restrict__ bq,
    const float* __restrict__ bv, const float* __restrict__ bo,
    float* __restrict__ W)
{
    int i = blockIdx.x * 256 + threadIdx.x;
    unsigned short* FH = (unsigned short*)(W + FRAGH);
    if (i < 608) {                        // QG[e][k] -> fragment col 32+k
        int e = i / 19, k = i % 19;
        float a = 0.f;
        for (int c = 0; c < 32; ++c) a += wq[e*32 + c] * W[XGK + k*32 + c];
        FH[fragidx(e, 32 + k)] = (unsigned short)b16r(a);
    } else if (i < 627) {                 // QGB[k]
        int k = i - 608;
        float a = 0.f;
        for (int c = 0; c < 32; ++c) a += bq[c] * W[XGK + k*32 + c];
        W[OFF_QGB + k] = a;
    } else if (i < 988) {                 // EGVB[k*20+j]
        int t = i - 627, k = t / 19, j = t % 19;
        float a = 0.f;
        for (int c = 0; c < 32; ++c) a += W[XGV + k*32 + c] * W[XB + c*19 + j];
        W[EGVB + k*20 + j] = a;
    } else if (i < 1007) {                // EGVB pad col
        int k = i - 988;
        W[EGVB + k*20 + 19] = 0.f;
    } else if (i < 1064) {                // MVB[m*19+j]
        int t = i - 1007, m = t / 19, j = t % 19;
        float a = 0.f;
        for (int c = 0; c < 32; ++c) a += W[XMV + m*32 + c] * W[XB + c*19 + j];
        W[OFF_MVB + t] = a;
    } else if (i < 1083) {                // CV[j]
        int j = i - 1064;
        float a = 0.f;
        for (int c = 0; c < 32; ++c) a += bv[c] * W[XB + c*19 + j];
        for (int d = 0; d < 32; ++d) a += bo[d] * W[XA2 + d*19 + j];
        W[OFF_CV + j] = a;
    }
}

// =====================================================================
// Main kernel. R0 region reused 3x: cpred stage -> HF (H cols f32) -> out
// stage. All global input/output for the hot arrays is coalesced float4.
// =====================================================================
__global__ __launch_bounds__(256, 2) void main_k(
    const float* __restrict__ feat,
    const float* __restrict__ sflow,
    const float* __restrict__ cpred,
    const float* __restrict__ Wg,
    float* __restrict__ out)
{
    const CONST_AS float* W = to_const(Wg);
    const int t = threadIdx.x, lane = t & 63, wvi = t >> 6;
    const int pblk = blockIdx.x * 256;

    __shared__ __align__(16) float R0[32 * 264];            // CP / HF / OB
    __shared__ __align__(16) unsigned short OH[41 * 264];   // logits/O1/QM bf16
    __shared__ __align__(16) float GV[380];                 // GVB 19x20

    if (t < 95) ((float4*)GV)[t] = ((const float4*)(Wg + EGVB))[t];

    // ---- phase 0: stage cpred slab (coalesced) and pull rows ----
    {
        const float4* src = (const float4*)(cpred + (long)pblk * 19);
        float4* dst = (float4*)R0;
        dst[t] = src[t];
        dst[256 + t] = src[256 + t];
        dst[512 + t] = src[512 + t];
        dst[768 + t] = src[768 + t];
        if (t < 192) dst[1024 + t] = src[1024 + t];
    }
    __syncthreads();
    float cp[19];
#pragma unroll
    for (int k = 0; k < 19; ++k) cp[k] = R0[t*19 + k];
    float m1 = cp[0];
#pragma unroll
    for (int k = 1; k < 19; ++k) m1 = fmaxf(m1, cp[k]);
    float sum1 = 0.f;
#pragma unroll
    for (int k = 0; k < 19; ++k) { cp[k] = __expf(cp[k] - m1); sum1 += cp[k]; }
    float r1 = 1.f / sum1;
#pragma unroll
    for (int k = 0; k < 19; ++k) cp[k] *= r1;
    __syncthreads();   // cp regs filled; R0 free for HF

    // ---- loop-invariant B fragments (7 x 16B per lane) ----
    const short8* FH8 = (const short8*)(Wg + FRAGH);
    const short8* FL8 = (const short8*)(Wg + FRAGL);
    short8 bh0 = FH8[0*64 + lane], bh1 = FH8[1*64 + lane];
    short8 bh2 = FH8[2*64 + lane], bh3 = FH8[3*64 + lane];
    short8 bh4 = FH8[4*64 + lane];
    short8 bl0 = FL8[0*64 + lane], bl1 = FL8[1*64 + lane];

    const int n15 = lane & 15, q = lane >> 4;

    // ---- phase 1: MFMA, 4 tiles of 16 points per wave ----
#pragma unroll
    for (int tile = 0; tile < 4; ++tile) {
        const int p0 = wvi*64 + tile*16;
        const float* fr = feat + (long)(pblk + p0 + n15) * 32 + q*8;
        float xv[8];
        {
            float4 va = *(const float4*)fr;
            float4 vb = *(const float4*)(fr + 4);
            xv[0]=va.x; xv[1]=va.y; xv[2]=va.z; xv[3]=va.w;
            xv[4]=vb.x; xv[5]=vb.y; xv[6]=vb.z; xv[7]=vb.w;
        }
        short8 ah, al;
#pragma unroll
        for (int j = 0; j < 8; ++j) {
            unsigned h = b16r(xv[j]);
            ah[j] = (short)h;
            al[j] = (short)b16r(xv[j] - fromb(h));
        }
        f32x4 z4 = {0.f, 0.f, 0.f, 0.f};
        f32x4 aH0, aH1, a2_, a3_, a4_;
        aH0 = __builtin_amdgcn_mfma_f32_16x16x32_bf16(ah, bh0, z4, 0, 0, 0);
        aH0 = __builtin_amdgcn_mfma_f32_16x16x32_bf16(ah, bl0, aH0, 0, 0, 0);
        aH0 = __builtin_amdgcn_mfma_f32_16x16x32_bf16(al, bh0, aH0, 0, 0, 0);
        aH1 = __builtin_amdgcn_mfma_f32_16x16x32_bf16(ah, bh1, z4, 0, 0, 0);
        aH1 = __builtin_amdgcn_mfma_f32_16x16x32_bf16(ah, bl1, aH1, 0, 0, 0);
        aH1 = __builtin_amdgcn_mfma_f32_16x16x32_bf16(al, bh1, aH1, 0, 0, 0);
        a2_ = __builtin_amdgcn_mfma_f32_16x16x32_bf16(ah, bh2, z4, 0, 0, 0);
        a3_ = __builtin_amdgcn_mfma_f32_16x16x32_bf16(ah, bh3, z4, 0, 0, 0);
        a4_ = __builtin_amdgcn_mfma_f32_16x16x32_bf16(ah, bh4, z4, 0, 0, 0);

        *(f32x4*)&R0[(n15)      * 264 + p0 + q*4] = aH0;   // H cols 0..15
        *(f32x4*)&R0[(16 + n15) * 264 + p0 + q*4] = aH1;   // H cols 16..31
        {
            unsigned d0, d1;
            d0 = b16r(a2_[0]) | (b16r(a2_[1]) << 16);
            d1 = b16r(a2_[2]) | (b16r(a2_[3]) << 16);
            *(uint2*)&OH[(n15) * 264 + p0 + q*4] = make_uint2(d0, d1);
            d0 = b16r(a3_[0]) | (b16r(a3_[1]) << 16);
            d1 = b16r(a3_[2]) | (b16r(a3_[3]) << 16);
            *(uint2*)&OH[(16 + n15) * 264 + p0 + q*4] = make_uint2(d0, d1);
            if (n15 <= 8) {
                d0 = b16r(a4_[0]) | (b16r(a4_[1]) << 16);
                d1 = b16r(a4_[2]) | (b16r(a4_[3]) << 16);
                *(uint2*)&OH[(32 + n15) * 264 + p0 + q*4] = make_uint2(d0, d1);
            }
        }
    }
    __syncthreads();

    // =========== phase 2: epilogue, thread t = point p ===========
    const long p = pblk + t;

    float s0 = sflow[p*3 + 0], s1 = sflow[p*3 + 1], s2 = sflow[p*3 + 2];
    bool tmask = (s0 != 0.f) | (s1 != 0.f) | (s2 != 0.f);

    // ---- gate from mfma H (split-bf16, err ~1e-4) ----
    const float TH = 1.3862943611198906f;   // ln(4): sigmoid<0.8
    float sacc = W[OFF_B2];
#pragma unroll
    for (int c = 0; c < 32; ++c) {
        float a = R0[c*264 + t];
        float h = fmaxf(fmaf(a, W[OFF_BNS + c], W[OFF_BNH + c]), 0.f);
        sacc = fmaf(h, W[OFF_SW2 + c], sacc);
    }
    // margin safety net: exact f32 recompute for near-threshold points
    bool nearthr = fabsf(sacc - TH) < 1e-3f;
    if (__ballot(nearthr) != 0ULL) {
        float f[32];
        const float4* fp4 = (const float4*)(feat + p*32);
#pragma unroll
        for (int g = 0; g < 8; ++g) {
            float4 v = fp4[g];
            f[g*4+0]=v.x; f[g*4+1]=v.y; f[g*4+2]=v.z; f[g*4+3]=v.w;
        }
        float sr = W[OFF_B2];
        for (int c = 0; c < 32; ++c) {
            float a = 0.f;
#pragma unroll
            for (int e = 0; e < 32; ++e) a = fmaf(f[e], W[OFF_SW1 + c*32 + e], a);
            float h = fmaxf(fmaf(a, W[OFF_BNS + c], W[OFF_BNH + c]), 0.f);
            sr = fmaf(h, W[OFF_SW2 + c], sr);
        }
        sacc = nearthr ? sr : sacc;
    }
    bool valid = tmask && (sacc < TH);

    // ---- logits / qs from mfma U ----
    float qm0 = fromb(OH[38*264 + t]) + W[OFF_QMB + 0];
    float qm1 = fromb(OH[39*264 + t]) + W[OFF_QMB + 1];
    float qm2 = fromb(OH[40*264 + t]) + W[OFF_QMB + 2];
    float qs = s0*qm0 + s1*qm1 + s2*qm2;

    const float RS = 0.17677669529663687f;  // 1/sqrt(32)
    float l[19];
#pragma unroll
    for (int k = 0; k < 19; ++k)
        l[k] = (cp[k] * (fromb(OH[k*264 + t]) + W[OFF_QGB + k] + qs)) * RS;

    float m2 = l[0];
#pragma unroll
    for (int k = 1; k < 19; ++k) m2 = fmaxf(m2, l[k]);
    float sum2 = 0.f;
#pragma unroll
    for (int k = 0; k < 19; ++k) { l[k] = __expf(l[k] - m2); sum2 += l[k]; }
    float r2 = 1.f / sum2;
    float Sw = 0.f;
#pragma unroll
    for (int k = 0; k < 19; ++k) { l[k] = l[k] * r2 * cp[k]; Sw += l[k]; }

    // ---- o = U_A1 + BB;  a2 = CV + Sw*(sf@MVB) + w@GVB ----
    float rv[19];
    float c0 = Sw * s0, c1 = Sw * s1, c2 = Sw * s2;
    float vg = valid ? 1.f : 0.f;
    float a2v[19];
#pragma unroll
    for (int j = 0; j < 19; ++j)
        a2v[j] = W[OFF_CV + j] + c0 * W[OFF_MVB + j]
               + c1 * W[OFF_MVB + 19 + j] + c2 * W[OFF_MVB + 38 + j];
#pragma unroll
    for (int k = 0; k < 19; ++k) {
        float lk = l[k];
#pragma unroll
        for (int j = 0; j < 19; ++j) a2v[j] = fmaf(lk, GV[k*20 + j], a2v[j]);
    }
#pragma unroll
    for (int j = 0; j < 19; ++j)
        rv[j] = fmaf(vg, a2v[j], fromb(OH[(19 + j)*264 + t]) + W[OFF_BB + j]);

    // ---- phase 3: stage out rows -> coalesced float4 stores ----
    __syncthreads();   // all R0(HF) reads done
#pragma unroll
    for (int j = 0; j < 19; ++j) R0[t*19 + j] = rv[j];
    __syncthreads();
    {
        const float4* src = (const float4*)R0;
        float4* dst = (float4*)(out + (long)pblk * 19);
        dst[t] = src[t];
        dst[256 + t] = src[256 + t];
        dst[512 + t] = src[512 + t];
        dst[768 + t] = src[768 + t];
        if (t < 192) dst[1024 + t] = src[1024 + t];
    }
}

// =====================================================================
extern "C" void kernel_launch(void* const* d_in, const int* in_sizes, int n_in,
                              void* d_out, int out_size, void* d_ws, size_t ws_size,
                              hipStream_t stream) {
    const float* feat  = (const float*)d_in[0];
    const float* sflow = (const float*)d_in[1];
    const float* cpred = (const float*)d_in[2];
    const float* z     = (const float*)d_in[3];
    const float* sw1   = (const float*)d_in[4];
    const float* bn_g  = (const float*)d_in[5];
    const float* bn_b  = (const float*)d_in[6];
    const float* bn_m  = (const float*)d_in[7];
    const float* bn_v  = (const float*)d_in[8];
    const float* sw2   = (const float*)d_in[9];
    const float* sb2   = (const float*)d_in[10];
    const float* wq    = (const float*)d_in[11];
    const float* bq    = (const float*)d_in[12];
    const float* wk    = (const float*)d_in[13];
    const float* bk    = (const float*)d_in[14];  (void)bk;
    const float* wv    = (const float*)d_in[15];
    const float* bv    = (const float*)d_in[16];
    const float* wo    = (const float*)d_in[17];
    const float* bo    = (const float*)d_in[18];
    const float* wt    = (const float*)d_in[19];
    const float* bt    = (const float*)d_in[20];
    const float* wout  = (const float*)d_in[21];
    const float* bout  = (const float*)d_in[22];
    const float* wgen  = (const float*)d_in[23];
    const float* bgen  = (const float*)d_in[24];

    float* W = (float*)d_ws;

    hipLaunchKernelGGL(pre_a, dim3(19), dim3(256), 0, stream,
                       z, sw1, bn_g, bn_b, bn_m, bn_v, sw2, sb2,
                       wk, wv, wt, bt, wout, bout, wgen, bgen, W);
    hipLaunchKernelGGL(pre_b, dim3(6), dim3(256), 0, stream,
                       wq, bq, wk, wv, wo, W);
    hipLaunchKernelGGL(pre_c, dim3(5), dim3(256), 0, stream,
                       wq, bq, bv, bo, W);

    hipLaunchKernelGGL(main_k, dim3(512), dim3(256), 0, stream,
                       feat, sflow, cpred, W, (float*)d_out);
}